// Round 1
// baseline (190.689 us; speedup 1.0000x reference)
//
#include <hip/hip_runtime.h>

#define WIN 7
#define OUT_W 126
#define OUT_H 16
#define IN_W 132   // OUT_W + WIN - 1
#define IN_H 22    // OUT_H + WIN - 1
#define RSTR 17    // colsum row stride: addr = c*RSTR + r ; 17 coprime 32 -> no LDS bank conflicts
#define H 384
#define W 384
#define OH 378
#define OW 378
#define NIMG 128
#define TX 3       // tiles per image in x: 3*126 = 378 exactly
#define TY 24      // tiles per image in y: ceil(378/16)
#define NBLK (TX * TY * NIMG)

__device__ __forceinline__ float wave_reduce(float v) {
#pragma unroll
    for (int off = 32; off > 0; off >>= 1) v += __shfl_down(v, off, 64);
    return v;
}

__global__ __launch_bounds__(256) void ssim_main(const float* __restrict__ pred,
                                                 const float* __restrict__ act,
                                                 float* __restrict__ partials) {
    __shared__ float cs_sx[IN_W * RSTR];
    __shared__ float cs_sy[IN_W * RSTR];
    __shared__ float cs_sxx[IN_W * RSTR];
    __shared__ float cs_syy[IN_W * RSTR];
    __shared__ float cs_sxy[IN_W * RSTR];
    __shared__ float red[4];

    const int t = threadIdx.x;
    const int img = blockIdx.z;
    const int x0 = blockIdx.x * OUT_W;
    const int y0 = blockIdx.y * OUT_H;
    const size_t base = (size_t)img * H * W;
    const float* xp = pred + base;
    const float* yp = act + base;

    // ---------- vertical pass: sliding 7-row sums per column ----------
    if (t < IN_W) {
        const int col = x0 + t;
        float xv[IN_H], yv[IN_H];
#pragma unroll
        for (int i = 0; i < IN_H; ++i) {
            const int row = y0 + i;
            const bool ok = row < H;   // only last y-tile clips
            xv[i] = ok ? xp[(size_t)row * W + col] : 0.f;
            yv[i] = ok ? yp[(size_t)row * W + col] : 0.f;
        }
        float sx = 0.f, sy = 0.f, sxx = 0.f, syy = 0.f, sxy = 0.f;
#pragma unroll
        for (int k = 0; k < WIN; ++k) {
            sx += xv[k];
            sy += yv[k];
            sxx = fmaf(xv[k], xv[k], sxx);
            syy = fmaf(yv[k], yv[k], syy);
            sxy = fmaf(xv[k], yv[k], sxy);
        }
        const int a = t * RSTR;
        cs_sx[a] = sx; cs_sy[a] = sy; cs_sxx[a] = sxx; cs_syy[a] = syy; cs_sxy[a] = sxy;
#pragma unroll
        for (int r = 1; r < OUT_H; ++r) {
            const float xn = xv[r + 6], yn = yv[r + 6];
            const float xo = xv[r - 1], yo = yv[r - 1];
            sx += xn - xo;
            sy += yn - yo;
            sxx = fmaf(xn, xn, fmaf(-xo, xo, sxx));
            syy = fmaf(yn, yn, fmaf(-yo, yo, syy));
            sxy = fmaf(xn, yn, fmaf(-xo, yo, sxy));
            cs_sx[a + r] = sx; cs_sy[a + r] = sy; cs_sxx[a + r] = sxx;
            cs_syy[a + r] = syy; cs_sxy[a + r] = sxy;
        }
    }
    __syncthreads();

    // ---------- horizontal pass: sliding 7-col sums + SSIM ----------
    const int r = t & 15;    // row within tile
    const int g = t >> 4;    // column group: outputs g*8 .. g*8+7
    const int c0 = g * 8;
    const int orow = y0 + r;

    const float INV = 1.0f / 49.0f;
    const float CN = 49.0f / 48.0f;
    const float C1f = 0.01f * 0.01f;
    const float C2f = 0.03f * 0.03f;

    float accS = 0.f;
    if (orow < OH) {
        float sx = 0.f, sy = 0.f, sxx = 0.f, syy = 0.f, sxy = 0.f;
#pragma unroll
        for (int k = 0; k < WIN - 1; ++k) {
            const int a = (c0 + k) * RSTR + r;
            sx += cs_sx[a]; sy += cs_sy[a]; sxx += cs_sxx[a];
            syy += cs_syy[a]; sxy += cs_sxy[a];
        }
#pragma unroll
        for (int k = 0; k < 8; ++k) {
            const int j = c0 + k;
            if (j < OUT_W) {
                const int an = (j + 6) * RSTR + r;
                sx += cs_sx[an]; sy += cs_sy[an]; sxx += cs_sxx[an];
                syy += cs_syy[an]; sxy += cs_sxy[an];

                const float ux = sx * INV, uy = sy * INV;
                const float uxx = sxx * INV, uyy = syy * INV, uxy = sxy * INV;
                const float ux2 = ux * ux, uy2 = uy * uy, uxuy = ux * uy;
                const float vx = CN * (uxx - ux2);
                const float vy = CN * (uyy - uy2);
                const float vxy = CN * (uxy - uxuy);
                const float num = fmaf(2.f, uxuy, C1f) * fmaf(2.f, vxy, C2f);
                const float den = (ux2 + uy2 + C1f) * (vx + vy + C2f);
                accS += num / den;

                const int ao = j * RSTR + r;
                sx -= cs_sx[ao]; sy -= cs_sy[ao]; sxx -= cs_sxx[ao];
                syy -= cs_syy[ao]; sxy -= cs_sxy[ao];
            }
        }
    }

    // ---------- block reduction ----------
    const float wsum = wave_reduce(accS);
    if ((t & 63) == 0) red[t >> 6] = wsum;
    __syncthreads();
    if (t == 0) {
        const float bsum = red[0] + red[1] + red[2] + red[3];
        partials[blockIdx.x + TX * (blockIdx.y + TY * blockIdx.z)] = bsum;
    }
}

__global__ __launch_bounds__(256) void ssim_finalize(const float* __restrict__ partials,
                                                     float* __restrict__ out) {
    __shared__ double red[256];
    const int t = threadIdx.x;
    double s = 0.0;
    for (int i = t; i < NBLK; i += 256) s += (double)partials[i];
    red[t] = s;
    __syncthreads();
#pragma unroll
    for (int off = 128; off > 0; off >>= 1) {
        if (t < off) red[t] += red[t + off];
        __syncthreads();
    }
    if (t == 0) out[0] = (float)(red[0] / ((double)NIMG * OH * OW));
}

extern "C" void kernel_launch(void* const* d_in, const int* in_sizes, int n_in,
                              void* d_out, int out_size, void* d_ws, size_t ws_size,
                              hipStream_t stream) {
    const float* pred = (const float*)d_in[0];
    const float* act  = (const float*)d_in[1];
    float* partials = (float*)d_ws;          // NBLK floats, fully overwritten each call
    dim3 grid(TX, TY, NIMG);
    ssim_main<<<grid, 256, 0, stream>>>(pred, act, partials);
    ssim_finalize<<<1, 256, 0, stream>>>(partials, (float*)d_out);
}

// Round 2
// 169.988 us; speedup vs baseline: 1.1218x; 1.1218x over previous
//
#include <hip/hip_runtime.h>

#define WIN 7
#define OUT_W 126
#define OUT_H 15
#define IN_W 132    // OUT_W + 6
#define IN_H 21     // OUT_H + 6
#define PITCH 132   // LDS row pitch in words; 132%32==4 -> even bank spread for b128 reads
#define AELEM (OUT_H * PITCH)   // 1980 floats per array
#define H 384
#define W 384
#define OH 378
#define OW 378
#define NIMG 128
#define TX 3        // 3*126 = 378 exactly
#define TY 26       // 25*15=375, last tile 3 rows
#define NBLK (TX * TY * NIMG)   // 9984

__device__ __forceinline__ float wave_reduce(float v) {
#pragma unroll
    for (int off = 32; off > 0; off >>= 1) v += __shfl_down(v, off, 64);
    return v;
}

__global__ __launch_bounds__(256, 4) void ssim_main(const float* __restrict__ pred,
                                                    const float* __restrict__ act,
                                                    float* __restrict__ partials) {
    // 5 arrays (sx, sy, sxx, syy, sxy), row-major [OUT_H][PITCH], +16 pad for
    // group-15 b128 overread (values masked, must not fault).
    __shared__ __align__(16) float cs[5 * AELEM + 16];
    __shared__ float red[4];

    const int t = threadIdx.x;
    const int img = blockIdx.z;
    const int x0 = blockIdx.x * OUT_W;
    const int y0 = blockIdx.y * OUT_H;
    const size_t base = (size_t)img * H * W;

    // ---------- vertical pass: sliding 7-row sums per column ----------
    if (t < IN_W) {
        const int col = x0 + t;                       // <= 383, always in-bounds
        const float* xc = pred + base + col;
        const float* yc = act + base + col;
        float xv[IN_H], yv[IN_H];
#pragma unroll
        for (int i = 0; i < IN_H; ++i) {
            const int row = y0 + i;
            const bool ok = row < H;                  // only last y-tile clips
            xv[i] = ok ? xc[(size_t)row * W] : 0.f;
            yv[i] = ok ? yc[(size_t)row * W] : 0.f;
        }
        float sx = 0.f, sy = 0.f, sxx = 0.f, syy = 0.f, sxy = 0.f;
#pragma unroll
        for (int k = 0; k < WIN; ++k) {
            sx += xv[k];
            sy += yv[k];
            sxx = fmaf(xv[k], xv[k], sxx);
            syy = fmaf(yv[k], yv[k], syy);
            sxy = fmaf(xv[k], yv[k], sxy);
        }
        cs[0 * AELEM + t] = sx;
        cs[1 * AELEM + t] = sy;
        cs[2 * AELEM + t] = sxx;
        cs[3 * AELEM + t] = syy;
        cs[4 * AELEM + t] = sxy;
#pragma unroll
        for (int r = 1; r < OUT_H; ++r) {
            const float xn = xv[r + 6], yn = yv[r + 6];
            const float xo = xv[r - 1], yo = yv[r - 1];
            sx += xn - xo;
            sy += yn - yo;
            sxx = fmaf(xn, xn, fmaf(-xo, xo, sxx));
            syy = fmaf(yn, yn, fmaf(-yo, yo, syy));
            sxy = fmaf(xn, yn, fmaf(-xo, yo, sxy));
            const int a = r * PITCH + t;
            cs[0 * AELEM + a] = sx;
            cs[1 * AELEM + a] = sy;
            cs[2 * AELEM + a] = sxx;
            cs[3 * AELEM + a] = syy;
            cs[4 * AELEM + a] = sxy;
        }
    }
    __syncthreads();

    // ---------- horizontal pass: b128 loads + register sliding ----------
    const int r = t & 15;        // tile row (r==15 idle)
    const int g = t >> 4;        // column group; outputs g*8 .. g*8+7
    const int c0 = g * 8;        // b128-aligned (pitch, c0, base all %4==0 words)

    const float C1B = 0.2401f;   // C1 * 49^2
    const float C2B = 2.1168f;   // C2 * 48*49

    float acc = 0.f;
    if (r < OUT_H && (y0 + r) < OH) {
        float S[5][8];
#pragma unroll
        for (int a = 0; a < 5; ++a) {
            const float* bp = &cs[a * AELEM + r * PITCH + c0];
            const float4 q0 = *(const float4*)(bp);
            const float4 q1 = *(const float4*)(bp + 4);
            const float4 q2 = *(const float4*)(bp + 8);
            const float4 q3 = *(const float4*)(bp + 12);
            const float v[16] = {q0.x, q0.y, q0.z, q0.w, q1.x, q1.y, q1.z, q1.w,
                                 q2.x, q2.y, q2.z, q2.w, q3.x, q3.y, q3.z, q3.w};
            float s = ((v[0] + v[1]) + (v[2] + v[3])) + ((v[4] + v[5]) + v[6]);
            S[a][0] = s;
#pragma unroll
            for (int j = 1; j < 8; ++j) {
                s += v[j + 6] - v[j - 1];
                S[a][j] = s;
            }
        }
        const int nmax = OUT_W - c0;      // 8 for groups 0..14, 6 for group 15
#pragma unroll
        for (int j = 0; j < 8; ++j) {
            if (j < nmax) {
                const float Sx = S[0][j], Sy = S[1][j];
                const float Sxx = S[2][j], Syy = S[3][j], Sxy = S[4][j];
                const float p = Sx * Sy;
                const float q = fmaf(Sx, Sx, Sy * Sy);
                const float n1 = fmaf(2.f, p, C1B);
                const float n2 = fmaf(98.f, Sxy, fmaf(-2.f, p, C2B));
                const float d1 = q + C1B;
                const float d2 = fmaf(49.f, Sxx + Syy, C2B - q);
                acc = fmaf(n1 * n2, __builtin_amdgcn_rcpf(d1 * d2), acc);
            }
        }
    }

    // ---------- block reduction ----------
    const float wsum = wave_reduce(acc);
    if ((t & 63) == 0) red[t >> 6] = wsum;
    __syncthreads();
    if (t == 0) {
        partials[blockIdx.x + TX * (blockIdx.y + TY * blockIdx.z)] =
            red[0] + red[1] + red[2] + red[3];
    }
}

__global__ __launch_bounds__(1024) void ssim_finalize(const float* __restrict__ partials,
                                                      float* __restrict__ out) {
    __shared__ double red[1024];
    const int t = threadIdx.x;
    double s = 0.0;
    for (int i = t; i < NBLK; i += 1024) s += (double)partials[i];
    red[t] = s;
    __syncthreads();
#pragma unroll
    for (int off = 512; off > 0; off >>= 1) {
        if (t < off) red[t] += red[t + off];
        __syncthreads();
    }
    if (t == 0) out[0] = (float)(red[0] / ((double)NIMG * OH * OW));
}

extern "C" void kernel_launch(void* const* d_in, const int* in_sizes, int n_in,
                              void* d_out, int out_size, void* d_ws, size_t ws_size,
                              hipStream_t stream) {
    const float* pred = (const float*)d_in[0];
    const float* act  = (const float*)d_in[1];
    float* partials = (float*)d_ws;           // NBLK floats, fully overwritten each call
    dim3 grid(TX, TY, NIMG);
    ssim_main<<<grid, 256, 0, stream>>>(pred, act, partials);
    ssim_finalize<<<1, 1024, 0, stream>>>(partials, (float*)d_out);
}